// Round 2
// baseline (687.487 us; speedup 1.0000x reference)
//
#include <hip/hip_runtime.h>
#include <hip/hip_bf16.h>

#define DIM  1024
#define RANK 256
#define NTOK 16384   // BATCH * SEQ = 4 * 4096

typedef __attribute__((ext_vector_type(8))) short short8;   // 8 bf16 = 4 VGPRs
typedef __attribute__((ext_vector_type(4))) float f32x4;

__device__ __forceinline__ short f2bf(float f) {
    __hip_bfloat16 h = __float2bfloat16(f);   // round-to-nearest-even
    return *(short*)&h;
}

// ---------------------------------------------------------------------------
// Pass 0a: Bt[d][r] = bf16(B[r][d])   (fp32 [256][1024] -> bf16 [1024][256])
// Lanes sweep consecutive d -> coalesced fp32 reads; 16 B bf16 writes.
// ---------------------------------------------------------------------------
__global__ void bt_kernel(const float* __restrict__ B,
                          __hip_bfloat16* __restrict__ Bt) {
    int idx   = blockIdx.x * blockDim.x + threadIdx.x;   // [0, 32768)
    int dtile = idx >> 11;          // 16 tiles of 64 cols
    int w     = idx & 2047;
    int d     = dtile * 64 + (w & 63);
    int r0    = (w >> 6) * 8;       // 32 groups of 8 rows
    short8 v;
#pragma unroll
    for (int j = 0; j < 8; ++j)
        ((short*)&v)[j] = f2bf(B[(r0 + j) * DIM + d]);
    *(short8*)((short*)Bt + d * RANK + r0) = v;
}

// ---------------------------------------------------------------------------
// Pass 0b: Ag[t][r] = bf16(A[x[t]][r])   (gather + downconvert, contiguous out)
// 32 threads per token, 8 ranks each: 32B fp32 read/lane, 16B bf16 write/lane.
// ---------------------------------------------------------------------------
__global__ void ag_kernel(const int* __restrict__ x,
                          const float* __restrict__ A,
                          __hip_bfloat16* __restrict__ Ag) {
    int idx = blockIdx.x * blockDim.x + threadIdx.x;   // [0, 16384*32)
    int t   = idx >> 5;
    int r0  = (idx & 31) * 8;
    int tok = x[t];
    const float* src = A + (long)tok * RANK + r0;
    short8 v;
#pragma unroll
    for (int j = 0; j < 8; ++j)
        ((short*)&v)[j] = f2bf(src[j]);
    *(short8*)((short*)Ag + t * RANK + r0) = v;
}

// ---------------------------------------------------------------------------
// Pass 1: Out[t][d] = W[x[t]][d] + Ag[t][:] @ Bt[d][:]   (fp32 out)
// Grid: (NTOK/128) x (DIM/128); block = 256 threads = 4 waves in 2x2.
// Wave tile 64x64 = 4x4 frags of 16x16; K = 256 = 8 MFMA k-steps.
// Operands direct-from-global (Ag/Bt are L2/L3 resident; no LDS staging).
// ---------------------------------------------------------------------------
__global__ void emb_gemm_kernel(const int* __restrict__ x,
                                const float* __restrict__ W,
                                const __hip_bfloat16* __restrict__ Ag,
                                const __hip_bfloat16* __restrict__ Bt,
                                float* __restrict__ out) {
    __shared__ int xs[128];
    const int t0  = blockIdx.x * 128;
    const int n0  = blockIdx.y * 128;
    const int tid = threadIdx.x;

    if (tid < 128) xs[tid] = x[t0 + tid];
    __syncthreads();

    const int lane = tid & 63;
    const int wv   = tid >> 6;
    const int wi   = wv >> 1;      // token-dim half (0..1)
    const int wj   = wv & 1;       // dim half (0..1)
    const int l15  = lane & 15;
    const int quad = lane >> 4;

    // A-operand: frag[j] = Ag[t0 + row][k0 + quad*8 + j]  (contiguous rows)
    const short* aptr[4];
#pragma unroll
    for (int i = 0; i < 4; ++i)
        aptr[i] = (const short*)Ag + (t0 + wi * 64 + i * 16 + l15) * RANK + quad * 8;
    // B-operand: frag[j] = B[k][col] = Bt[col][k0 + quad*8 + j]
    const short* bptr[4];
#pragma unroll
    for (int j = 0; j < 4; ++j)
        bptr[j] = (const short*)Bt + (n0 + wj * 64 + j * 16 + l15) * RANK + quad * 8;

    f32x4 acc[4][4] = {};

#pragma unroll
    for (int ks = 0; ks < 8; ++ks) {      // k0 = ks*32
        short8 a[4], b[4];
#pragma unroll
        for (int i = 0; i < 4; ++i) a[i] = *(const short8*)(aptr[i] + ks * 32);
#pragma unroll
        for (int j = 0; j < 4; ++j) b[j] = *(const short8*)(bptr[j] + ks * 32);
#pragma unroll
        for (int i = 0; i < 4; ++i)
#pragma unroll
            for (int j = 0; j < 4; ++j)
                acc[i][j] = __builtin_amdgcn_mfma_f32_16x16x32_bf16(
                    a[i], b[j], acc[i][j], 0, 0, 0);
    }

    // Epilogue: C/D layout row = quad*4 + reg, col = lane&15 (m89/m91).
    // 16 consecutive lanes cover a 64 B segment of W / out -> coalesced.
#pragma unroll
    for (int i = 0; i < 4; ++i) {
#pragma unroll
        for (int jj = 0; jj < 4; ++jj) {
            const int lr   = wi * 64 + i * 16 + quad * 4 + jj;   // local row
            const int tokr = xs[lr];
            const float* wrow = W + (long)tokr * DIM;
            float* orow = out + (long)(t0 + lr) * DIM;
#pragma unroll
            for (int j = 0; j < 4; ++j) {
                const int c = n0 + wj * 64 + j * 16 + l15;
                orow[c] = wrow[c] + acc[i][j][jj];
            }
        }
    }
}

extern "C" void kernel_launch(void* const* d_in, const int* in_sizes, int n_in,
                              void* d_out, int out_size, void* d_ws, size_t ws_size,
                              hipStream_t stream) {
    const int*   x = (const int*)d_in[0];
    const float* W = (const float*)d_in[1];
    const float* A = (const float*)d_in[2];
    const float* B = (const float*)d_in[3];
    float* out     = (float*)d_out;

    __hip_bfloat16* Bt = (__hip_bfloat16*)d_ws;                       // 512 KB
    __hip_bfloat16* Ag = (__hip_bfloat16*)((char*)d_ws + DIM * RANK * sizeof(short)); // 8 MB

    bt_kernel<<<128, 256, 0, stream>>>(B, Bt);
    ag_kernel<<<NTOK * 32 / 256, 256, 0, stream>>>(x, A, Ag);
    emb_gemm_kernel<<<dim3(NTOK / 128, DIM / 128), 256, 0, stream>>>(x, W, Ag, Bt, out);
}